// Round 3
// baseline (3989.344 us; speedup 1.0000x reference)
//
#include <hip/hip_runtime.h>

typedef __bf16 bf16x8 __attribute__((ext_vector_type(8)));
typedef float f32x4 __attribute__((ext_vector_type(4)));

__device__ __forceinline__ float sigmoidf_fast(float x) {
  return 1.f / (1.f + __expf(-x));
}
__device__ __forceinline__ float tanhf_fast(float x) {
  float e = __expf(2.f * x);
  return 1.f - 2.f / (e + 1.f);
}

// Wt[tap][oc][ci] = (bf16)W[oc][ci][tap], tap = ky*3+kx  (k-contiguous A-fragments)
__global__ void transpose_w_kernel(const float* __restrict__ Wsrc,
                                   __bf16* __restrict__ Wt, int C4, int C2) {
  int idx = blockIdx.x * 256 + threadIdx.x;
  int total = C4 * C2 * 9;
  if (idx >= total) return;
  int tap = idx / (C4 * C2);
  int rem = idx - tap * (C4 * C2);
  int oc = rem / C2;
  int ci = rem - oc * C2;
  Wt[idx] = (__bf16)Wsrc[(oc * C2 + ci) * 9 + tap];
}

__global__ void combine_kernel(const float* __restrict__ hf,
                               const float* __restrict__ hb,
                               float* __restrict__ out, int n) {
  int idx = blockIdx.x * 256 + threadIdx.x;
  if (idx >= n) return;
  out[idx] = (hf[idx] + hb[idx]) * 0.5f;
}

// One block = (dir d, batch b, row-pair y0..y0+1). 512 threads = 2 row-groups
// x 4 waves. Wave owns its oc-tiles for all 4 gates -> gate fusion in registers.
// LDS holds bf16 input transposed [row][slot][ci] so B-fragments are ds_read_b128.
// Grid puts d in blockIdx.x (lowest linear bit) so round-robin block->XCD gives
// each XCD one dir's weights (<4MB) -> L2-resident A-fragments.
template <int C, int H, int W, int SUB, int NT>
__global__ __launch_bounds__(512, 4)
void convlstm_step_kernel(const float* __restrict__ x_t,     // [B][C][H][W] f32
                          const int* __restrict__ mask_t,    // [B]
                          const __bf16* __restrict__ Wt,     // [2][9][4C][2C] bf16
                          const float* __restrict__ bias_f,  // [4C]
                          const float* __restrict__ bias_b,  // [4C]
                          const float* __restrict__ h_in,    // [2][B][C][H][W] f32
                          float* __restrict__ h_out,         // [2][B][C][H][W] f32
                          float* __restrict__ c_st)          // [2][B][C][H][W] f32
{
  constexpr int B = 8;
  constexpr int C2 = 2 * C, C4 = 4 * C;
  constexpr int COLS = W + 2;       // image x at slot x+1; slots 0, W+1 zero halo
  constexpr int C2p = C2 + 8;       // ci leading dim (mult of 8 -> 16B-aligned b128)
  constexpr int PLANE = H * W;
  constexpr int CHW = C * PLANE;
  constexpr int W4 = W / 4;

  __shared__ __bf16 sT[4 * COLS * C2p];   // rows y0-1 .. y0+2

  const int d = blockIdx.x;
  const int y0 = blockIdx.y * 2;
  const int b = blockIdx.z;
  const int tid = threadIdx.x;

  const float* hin_b = h_in + (size_t)(d * B + b) * CHW;
  float* hout_b = h_out + (size_t)(d * B + b) * CHW;

  if (mask_t[b] <= 0) {
    // state carry: copy 2 rows of h (c is in-place, untouched)
    constexpr int UN = C * 2 * W4;
    for (int u = tid; u < UN; u += 512) {
      int c = u / (2 * W4);
      int rem = u - c * 2 * W4;
      int r = rem / W4;
      int xu = rem - r * W4;
      size_t off = (size_t)c * PLANE + (size_t)(y0 + r) * W + xu * 4;
      *reinterpret_cast<float4*>(hout_b + off) =
          *reinterpret_cast<const float4*>(hin_b + off);
    }
    return;
  }

  // ---- stage bf16([x | h]) rows y0-1..y0+2 into transposed LDS ----
  const float* x_b = x_t + (size_t)b * CHW;
  constexpr int UNITS = C2 * 4 * W4;
  for (int u = tid; u < UNITS; u += 512) {
    int ci = u / (4 * W4);             // xu fastest -> coalesced global reads
    int rem = u - ci * 4 * W4;
    int rr = rem / W4;
    int xu = rem - rr * W4;
    int yy = y0 + rr - 1;
    float4 v = make_float4(0.f, 0.f, 0.f, 0.f);
    if (yy >= 0 && yy < H) {
      const float* src = (ci < C)
          ? (x_b + (size_t)ci * PLANE + (size_t)yy * W + xu * 4)
          : (hin_b + (size_t)(ci - C) * PLANE + (size_t)yy * W + xu * 4);
      v = *reinterpret_cast<const float4*>(src);
    }
    int idx = (rr * COLS + 4 * xu + 1) * C2p + ci;
    sT[idx] = (__bf16)v.x;
    sT[idx + C2p] = (__bf16)v.y;
    sT[idx + 2 * C2p] = (__bf16)v.z;
    sT[idx + 3 * C2p] = (__bf16)v.w;
  }
  // x halo: slots 0 and W+1 zero
  for (int u = tid; u < C2 * 4 * 2; u += 512) {
    int ci = u >> 3;
    int rem = u & 7;
    int rr = rem >> 1;
    int slot = (rem & 1) ? (W + 1) : 0;
    sT[(rr * COLS + slot) * C2p + ci] = (__bf16)0.f;
  }
  __syncthreads();

  const int lane = tid & 63;
  const int wv = tid >> 6;
  const int rg = wv >> 2;    // row-group: 0 -> row y0, 1 -> row y0+1
  const int wvr = wv & 3;    // wave within row-group
  const int n = lane & 15;   // A: m / B: n / D: col (= x within 16-tile)
  const int q = lane >> 4;   // k quad

  f32x4 acc[4][SUB][NT];
  f32x4 zero = {0.f, 0.f, 0.f, 0.f};
#pragma unroll
  for (int g = 0; g < 4; ++g)
#pragma unroll
    for (int s = 0; s < SUB; ++s)
#pragma unroll
      for (int nt = 0; nt < NT; ++nt) acc[g][s][nt] = zero;

  const __bf16* Wtd = Wt + (size_t)d * (9 * C4 * C2);

  for (int ky = 0; ky < 3; ++ky) {
    const int rowbase = (rg + ky) * COLS;
#pragma unroll
    for (int kx = 0; kx < 3; ++kx) {
      const int tap = ky * 3 + kx;
      const int cbase = (rowbase + n + kx) * C2p + q * 8;
#pragma unroll
      for (int ci0 = 0; ci0 < C2; ci0 += 32) {
        // B fragments: one ds_read_b128 per n-tile (k = ci0+q*8+j contiguous)
        bf16x8 bfr[NT];
#pragma unroll
        for (int nt = 0; nt < NT; ++nt)
          bfr[nt] = *reinterpret_cast<const bf16x8*>(
              &sT[cbase + nt * 16 * C2p + ci0]);
        // A fragments: 16B contiguous from tap-major weights (L2-resident)
        bf16x8 afr[4][SUB];
#pragma unroll
        for (int g = 0; g < 4; ++g) {
#pragma unroll
          for (int s = 0; s < SUB; ++s) {
            int oc = g * C + (wvr * SUB + s) * 16 + n;
            afr[g][s] = *reinterpret_cast<const bf16x8*>(
                Wtd + (size_t)(tap * C4 + oc) * C2 + ci0 + q * 8);
          }
        }
#pragma unroll
        for (int g = 0; g < 4; ++g)
#pragma unroll
          for (int s = 0; s < SUB; ++s)
#pragma unroll
            for (int nt = 0; nt < NT; ++nt)
              acc[g][s][nt] = __builtin_amdgcn_mfma_f32_16x16x32_bf16(
                  afr[g][s], bfr[nt], acc[g][s][nt], 0, 0, 0);
      }
    }
  }

  // ---- fused LSTM gate epilogue (D: col = n = x, row = q*4+reg = channel) ----
  float* c_b = c_st + (size_t)(d * B + b) * CHW;
  const float* bias = (d == 0) ? bias_f : bias_b;
  const int y = y0 + rg;
#pragma unroll
  for (int s = 0; s < SUB; ++s) {
#pragma unroll
    for (int r = 0; r < 4; ++r) {
      const int c = (wvr * SUB + s) * 16 + q * 4 + r;
      const float bi = bias[0 * C + c];
      const float bff = bias[1 * C + c];
      const float bo = bias[2 * C + c];
      const float bg = bias[3 * C + c];
#pragma unroll
      for (int nt = 0; nt < NT; ++nt) {
        const int x = nt * 16 + n;
        const size_t off = (size_t)c * PLANE + (size_t)y * W + x;
        const float vi = acc[0][s][nt][r] + bi;
        const float vf = acc[1][s][nt][r] + bff;
        const float vo = acc[2][s][nt][r] + bo;
        const float vg = acc[3][s][nt][r] + bg;
        const float cn = sigmoidf_fast(vf) * c_b[off] + sigmoidf_fast(vi) * tanhf_fast(vg);
        c_b[off] = cn;
        hout_b[off] = sigmoidf_fast(vo) * tanhf_fast(cn);
      }
    }
  }
}

extern "C" void kernel_launch(void* const* d_in, const int* in_sizes, int n_in,
                              void* d_out, int out_size, void* d_ws, size_t ws_size,
                              hipStream_t stream) {
  const float* feat0 = (const float*)d_in[0];
  const float* feat1 = (const float*)d_in[1];
  const int* mask = (const int*)d_in[2];
  const float* Wf0 = (const float*)d_in[3];
  const float* bf0 = (const float*)d_in[4];
  const float* Wb0 = (const float*)d_in[5];
  const float* bb0 = (const float*)d_in[6];
  const float* Wf1 = (const float*)d_in[7];
  const float* bf1 = (const float*)d_in[8];
  const float* Wb1 = (const float*)d_in[9];
  const float* bb1 = (const float*)d_in[10];

  const int T = 16;
  const size_t SZ0 = (size_t)8 * 64 * 64 * 64;   // per-(dir,buf) h elements, level 0
  const size_t SZ1 = (size_t)8 * 128 * 32 * 32;  // level 1
  const size_t WT0 = (size_t)9 * 256 * 128;      // per-dir transposed weights
  const size_t WT1 = (size_t)9 * 512 * 256;

  char* p = (char*)d_ws;
  __bf16* Wt0 = (__bf16*)p; p += 2 * WT0 * sizeof(__bf16);
  __bf16* Wt1 = (__bf16*)p; p += 2 * WT1 * sizeof(__bf16);
  float* h0 = (float*)p;    p += 4 * SZ0 * sizeof(float);   // [buf][dir][B][C][H][W]
  float* h1 = (float*)p;    p += 4 * SZ1 * sizeof(float);
  float* c0 = (float*)p;    p += 2 * SZ0 * sizeof(float);   // [dir][B][C][H][W]
  float* c1 = (float*)p;    p += 2 * SZ1 * sizeof(float);

  // zero-init h buf0 (both dirs) and c (ws is re-poisoned 0xAA before every call)
  hipMemsetAsync(h0, 0, 2 * SZ0 * sizeof(float), stream);
  hipMemsetAsync(h1, 0, 2 * SZ1 * sizeof(float), stream);
  hipMemsetAsync(c0, 0, 2 * SZ0 * sizeof(float), stream);
  hipMemsetAsync(c1, 0, 2 * SZ1 * sizeof(float), stream);

  transpose_w_kernel<<<((int)WT0 + 255) / 256, 256, 0, stream>>>(Wf0, Wt0, 256, 128);
  transpose_w_kernel<<<((int)WT0 + 255) / 256, 256, 0, stream>>>(Wb0, Wt0 + WT0, 256, 128);
  transpose_w_kernel<<<((int)WT1 + 255) / 256, 256, 0, stream>>>(Wf1, Wt1, 512, 256);
  transpose_w_kernel<<<((int)WT1 + 255) / 256, 256, 0, stream>>>(Wb1, Wt1 + WT1, 512, 256);

  for (int t = 0; t < T; ++t) {
    const int pi = t & 1, po = 1 - pi;
    convlstm_step_kernel<64, 64, 64, 1, 4><<<dim3(2, 32, 8), 512, 0, stream>>>(
        feat0 + (size_t)t * SZ0, mask + t * 8, Wt0, bf0, bb0,
        h0 + (size_t)pi * 2 * SZ0, h0 + (size_t)po * 2 * SZ0, c0);
    convlstm_step_kernel<128, 32, 32, 2, 2><<<dim3(2, 16, 8), 512, 0, stream>>>(
        feat1 + (size_t)t * SZ1, mask + t * 8, Wt1, bf1, bb1,
        h1 + (size_t)pi * 2 * SZ1, h1 + (size_t)po * 2 * SZ1, c1);
  }

  // T=16 is even -> final states live in buf 0
  float* out = (float*)d_out;
  combine_kernel<<<((int)SZ0 + 255) / 256, 256, 0, stream>>>(h0, h0 + SZ0, out, (int)SZ0);
  combine_kernel<<<((int)SZ1 + 255) / 256, 256, 0, stream>>>(h1, h1 + SZ1, out + SZ0, (int)SZ1);
}

// Round 5
// 3425.419 us; speedup vs baseline: 1.1646x; 1.1646x over previous
//
#include <hip/hip_runtime.h>

typedef __bf16 bf16x8 __attribute__((ext_vector_type(8)));
typedef float f32x4 __attribute__((ext_vector_type(4)));

__device__ __forceinline__ float sigmoidf_fast(float x) {
  return 1.f / (1.f + __expf(-x));
}
__device__ __forceinline__ float tanhf_fast(float x) {
  float e = __expf(2.f * x);
  return 1.f - 2.f / (e + 1.f);
}

// Wt[tap][oc][ci] = (bf16)W[oc][ci][tap], tap = ky*3+kx  (k-contiguous A rows)
__global__ void transpose_w_kernel(const float* __restrict__ Wsrc,
                                   __bf16* __restrict__ Wt, int C4, int C2) {
  int idx = blockIdx.x * 256 + threadIdx.x;
  int total = C4 * C2 * 9;
  if (idx >= total) return;
  int tap = idx / (C4 * C2);
  int rem = idx - tap * (C4 * C2);
  int oc = rem / C2;
  int ci = rem - oc * C2;
  Wt[idx] = (__bf16)Wsrc[(oc * C2 + ci) * 9 + tap];
}

__global__ void combine_kernel(const float* __restrict__ hf,
                               const float* __restrict__ hb,
                               float* __restrict__ out, int n) {
  int idx = blockIdx.x * 256 + threadIdx.x;
  if (idx >= n) return;
  out[idx] = (hf[idx] + hb[idx]) * 0.5f;
}

// level-1 LDS: image 6*34*264*2 = 107712 B + A-slab 512*40*2 = 40960 B
constexpr int SMEM_BYTES = 148672;

// One block = (dir d, batch b, OROWS output rows). 512 thr = 8 waves =
// 2 N-groups (rg) x 4 c-waves (wvr). Wave-tile: M = 4 gates x SUB x 16,
// N = 64 (NT=4 tiles of 16). Weights staged per (tap,ci0) chunk into padded
// LDS (shared across all 8 waves — the round-3 bottleneck was per-wave
// private A-streams from L2). Image staged once, transposed [row][slot][ci].
template <int C, int H, int W, int SUB, int OROWS>
__device__ __forceinline__ void convlstm_block(
    char* smem, const float* __restrict__ x_t, int maskv,
    const __bf16* __restrict__ Wt, const float* __restrict__ bias,
    const float* __restrict__ h_in, float* __restrict__ h_out,
    float* __restrict__ c_st, int d, int b, int y0)
{
  constexpr int B = 8, C2 = 2 * C, C4 = 4 * C;
  constexpr int COLS = W + 2;      // image x at slot x+1; slots 0, W+1 zero halo
  constexpr int C2p = C2 + 8;      // ci leading dim (mult of 8 -> aligned b128)
  constexpr int IMR = OROWS + 2;   // staged image rows y0-1 .. y0+OROWS
  constexpr int PLANE = H * W, CHW = C * PLANE;
  constexpr int AP = 40;           // A-slab ci stride: 32 + 8 pad (bank spread)
  constexpr int CTPR = (W / 16) < 4 ? (W / 16) : 4;  // col-tiles per row
  constexpr int RPG = OROWS / 2;   // rows per N-group
  constexpr int W4 = W / 4;

  __bf16* sT = (__bf16*)smem;
  __bf16* sA = (__bf16*)(smem + (size_t)IMR * COLS * C2p * 2);

  const int tid = threadIdx.x;
  const float* hin_b = h_in + (size_t)(d * B + b) * CHW;
  float* hout_b = h_out + (size_t)(d * B + b) * CHW;

  if (maskv <= 0) {
    // state carry: copy OROWS rows of h (c in-place, untouched)
    constexpr int UN = C * OROWS * W4;
    for (int u = tid; u < UN; u += 512) {
      int c = u / (OROWS * W4);
      int rem = u - c * (OROWS * W4);
      int r = rem / W4, xu = rem - r * W4;
      size_t off = (size_t)c * PLANE + (size_t)(y0 + r) * W + xu * 4;
      *reinterpret_cast<float4*>(hout_b + off) =
          *reinterpret_cast<const float4*>(hin_b + off);
    }
    return;
  }

  // ---- stage bf16([x | h]) rows y0-1..y0+OROWS into transposed LDS ----
  const float* x_b = x_t + (size_t)b * CHW;
  constexpr int UNITS = C2 * IMR * W4;
  for (int u = tid; u < UNITS; u += 512) {
    int ci = u / (IMR * W4);
    int rem = u - ci * (IMR * W4);
    int rr = rem / W4, xu = rem - rr * W4;
    int yy = y0 + rr - 1;
    float4 v = make_float4(0.f, 0.f, 0.f, 0.f);
    if (yy >= 0 && yy < H) {
      const float* src = (ci < C)
          ? (x_b + (size_t)ci * PLANE + (size_t)yy * W + xu * 4)
          : (hin_b + (size_t)(ci - C) * PLANE + (size_t)yy * W + xu * 4);
      v = *reinterpret_cast<const float4*>(src);
    }
    int base = (rr * COLS + 4 * xu + 1) * C2p + ci;
    sT[base] = (__bf16)v.x;
    sT[base + C2p] = (__bf16)v.y;
    sT[base + 2 * C2p] = (__bf16)v.z;
    sT[base + 3 * C2p] = (__bf16)v.w;
  }
  for (int u = tid; u < C2 * IMR * 2; u += 512) {
    int ci = u / (IMR * 2);
    int rem = u - ci * (IMR * 2);
    int rr = rem >> 1;
    int slot = (rem & 1) ? (W + 1) : 0;
    sT[(rr * COLS + slot) * C2p + ci] = (__bf16)0.f;
  }

  const int lane = tid & 63, wv = tid >> 6;
  const int rg = wv >> 2, wvr = wv & 3;
  const int n = lane & 15, q = lane >> 4;

  f32x4 acc[4][SUB][4];
  f32x4 zero = {0.f, 0.f, 0.f, 0.f};
#pragma unroll
  for (int g = 0; g < 4; ++g)
#pragma unroll
    for (int s = 0; s < SUB; ++s)
#pragma unroll
      for (int nt = 0; nt < 4; ++nt) acc[g][s][nt] = zero;

  const __bf16* Wtd = Wt + (size_t)d * (9 * C4 * C2);

  for (int tap = 0; tap < 9; ++tap) {
    const int ky = tap / 3, kx = tap - 3 * ky;
    for (int ci0 = 0; ci0 < C2; ci0 += 32) {
      __syncthreads();   // previous chunk's sA reads done (covers image stage 1st)
      // ---- stage A-slab [4C oc][32 ci] -> padded LDS (stride AP) ----
      // 32 ci = 64 B = 4 x uint4 per oc row (uint4 = 16 B = 8 bf16!)
      const __bf16* Wtap = Wtd + (size_t)tap * C4 * C2 + ci0;
      for (int u = tid; u < C4 * 4; u += 512) {
        int oc = u >> 2, quarter = (u & 3) << 3;   // elements 0,8,16,24
        *reinterpret_cast<uint4*>(sA + oc * AP + quarter) =
            *reinterpret_cast<const uint4*>(Wtap + (size_t)oc * C2 + quarter);
      }
      __syncthreads();

      // B fragments: one ds_read_b128 per n-tile
      bf16x8 bfr[4];
#pragma unroll
      for (int nt = 0; nt < 4; ++nt) {
        int rr = rg * RPG + nt / CTPR + ky;
        int slot = (nt % CTPR) * 16 + n + kx;
        bfr[nt] = *reinterpret_cast<const bf16x8*>(
            &sT[(rr * COLS + slot) * C2p + ci0 + q * 8]);
      }
      // A fragments from the shared LDS slab
      bf16x8 afr[4][SUB];
#pragma unroll
      for (int g = 0; g < 4; ++g)
#pragma unroll
        for (int s = 0; s < SUB; ++s) {
          int oc = g * C + (wvr * SUB + s) * 16 + n;
          afr[g][s] = *reinterpret_cast<const bf16x8*>(&sA[oc * AP + q * 8]);
        }
#pragma unroll
      for (int g = 0; g < 4; ++g)
#pragma unroll
        for (int s = 0; s < SUB; ++s)
#pragma unroll
          for (int nt = 0; nt < 4; ++nt)
            acc[g][s][nt] = __builtin_amdgcn_mfma_f32_16x16x32_bf16(
                afr[g][s], bfr[nt], acc[g][s][nt], 0, 0, 0);
    }
  }

  // ---- fused LSTM gate epilogue (D: col = n = x, row = q*4+reg = channel) ----
  float* c_b = c_st + (size_t)(d * B + b) * CHW;
  const int yb = y0 + rg * RPG;
#pragma unroll
  for (int s = 0; s < SUB; ++s) {
#pragma unroll
    for (int r = 0; r < 4; ++r) {
      const int c = (wvr * SUB + s) * 16 + q * 4 + r;
      const float bi = bias[0 * C + c];
      const float bff = bias[1 * C + c];
      const float bo = bias[2 * C + c];
      const float bg = bias[3 * C + c];
#pragma unroll
      for (int nt = 0; nt < 4; ++nt) {
        const int y = yb + nt / CTPR;
        const int x = (nt % CTPR) * 16 + n;
        const size_t off = (size_t)c * PLANE + (size_t)y * W + x;
        const float vi = acc[0][s][nt][r] + bi;
        const float vf = acc[1][s][nt][r] + bff;
        const float vo = acc[2][s][nt][r] + bo;
        const float vg = acc[3][s][nt][r] + bg;
        const float cn = sigmoidf_fast(vf) * c_b[off] + sigmoidf_fast(vi) * tanhf_fast(vg);
        c_b[off] = cn;
        hout_b[off] = sigmoidf_fast(vo) * tanhf_fast(cn);
      }
    }
  }
}

// Fused two-level step: blocks [0,128) = level-1 (big, scheduled first),
// [128,640) = level-0. dir = lowest grid bit -> XCD round-robin keeps each
// XCD on one dir's weights.
__global__ __launch_bounds__(512, 2)
void step_kernel(const float* __restrict__ x0, const float* __restrict__ x1,
                 const int* __restrict__ mask_t,
                 const __bf16* __restrict__ Wt0, const __bf16* __restrict__ Wt1,
                 const float* __restrict__ bf0, const float* __restrict__ bb0,
                 const float* __restrict__ bf1, const float* __restrict__ bb1,
                 const float* __restrict__ hin0, float* __restrict__ hout0,
                 float* __restrict__ c0,
                 const float* __restrict__ hin1, float* __restrict__ hout1,
                 float* __restrict__ c1)
{
  __shared__ __align__(16) char smem[SMEM_BYTES];
  const int idx = blockIdx.x;
  if (idx < 128) {
    int d = idx & 1, r = idx >> 1;
    int b = r & 7, yb = r >> 3;    // yb in [0,8): 4 rows each
    convlstm_block<128, 32, 32, 2, 4>(smem, x1, mask_t[b], Wt1,
        d == 0 ? bf1 : bb1, hin1, hout1, c1, d, b, yb * 4);
  } else {
    int j = idx - 128;
    int d = j & 1, r = j >> 1;
    int b = r & 7, yb = r >> 3;    // yb in [0,32): 2 rows each
    convlstm_block<64, 64, 64, 1, 2>(smem, x0, mask_t[b], Wt0,
        d == 0 ? bf0 : bb0, hin0, hout0, c0, d, b, yb * 2);
  }
}

extern "C" void kernel_launch(void* const* d_in, const int* in_sizes, int n_in,
                              void* d_out, int out_size, void* d_ws, size_t ws_size,
                              hipStream_t stream) {
  const float* feat0 = (const float*)d_in[0];
  const float* feat1 = (const float*)d_in[1];
  const int* mask = (const int*)d_in[2];
  const float* Wf0 = (const float*)d_in[3];
  const float* bf0 = (const float*)d_in[4];
  const float* Wb0 = (const float*)d_in[5];
  const float* bb0 = (const float*)d_in[6];
  const float* Wf1 = (const float*)d_in[7];
  const float* bf1 = (const float*)d_in[8];
  const float* Wb1 = (const float*)d_in[9];
  const float* bb1 = (const float*)d_in[10];

  const int T = 16;
  const size_t SZ0 = (size_t)8 * 64 * 64 * 64;   // per-(dir,buf) h elems, level 0
  const size_t SZ1 = (size_t)8 * 128 * 32 * 32;  // level 1
  const size_t WT0 = (size_t)9 * 256 * 128;      // per-dir transposed weights
  const size_t WT1 = (size_t)9 * 512 * 256;

  char* p = (char*)d_ws;
  __bf16* Wt0 = (__bf16*)p; p += 2 * WT0 * sizeof(__bf16);
  __bf16* Wt1 = (__bf16*)p; p += 2 * WT1 * sizeof(__bf16);
  float* h0 = (float*)p;    p += 4 * SZ0 * sizeof(float);   // [buf][dir][B][C][H][W]
  float* h1 = (float*)p;    p += 4 * SZ1 * sizeof(float);
  float* c0 = (float*)p;    p += 2 * SZ0 * sizeof(float);   // [dir][B][C][H][W]
  float* c1 = (float*)p;    p += 2 * SZ1 * sizeof(float);

  hipMemsetAsync(h0, 0, 2 * SZ0 * sizeof(float), stream);
  hipMemsetAsync(h1, 0, 2 * SZ1 * sizeof(float), stream);
  hipMemsetAsync(c0, 0, 2 * SZ0 * sizeof(float), stream);
  hipMemsetAsync(c1, 0, 2 * SZ1 * sizeof(float), stream);

  transpose_w_kernel<<<((int)WT0 + 255) / 256, 256, 0, stream>>>(Wf0, Wt0, 256, 128);
  transpose_w_kernel<<<((int)WT0 + 255) / 256, 256, 0, stream>>>(Wb0, Wt0 + WT0, 256, 128);
  transpose_w_kernel<<<((int)WT1 + 255) / 256, 256, 0, stream>>>(Wf1, Wt1, 512, 256);
  transpose_w_kernel<<<((int)WT1 + 255) / 256, 256, 0, stream>>>(Wb1, Wt1 + WT1, 512, 256);

  for (int t = 0; t < T; ++t) {
    const int pi = t & 1, po = 1 - pi;
    step_kernel<<<640, 512, 0, stream>>>(
        feat0 + (size_t)t * SZ0, feat1 + (size_t)t * SZ1, mask + t * 8,
        Wt0, Wt1, bf0, bb0, bf1, bb1,
        h0 + (size_t)pi * 2 * SZ0, h0 + (size_t)po * 2 * SZ0, c0,
        h1 + (size_t)pi * 2 * SZ1, h1 + (size_t)po * 2 * SZ1, c1);
  }

  // T=16 is even -> final states live in buf 0
  float* out = (float*)d_out;
  combine_kernel<<<((int)SZ0 + 255) / 256, 256, 0, stream>>>(h0, h0 + SZ0, out, (int)SZ0);
  combine_kernel<<<((int)SZ1 + 255) / 256, 256, 0, stream>>>(h1, h1 + SZ1, out + SZ0, (int)SZ1);
}

// Round 6
// 2283.010 us; speedup vs baseline: 1.7474x; 1.5004x over previous
//
#include <hip/hip_runtime.h>

typedef __bf16 bf16x8 __attribute__((ext_vector_type(8)));
typedef float f32x4 __attribute__((ext_vector_type(4)));

__device__ __forceinline__ float sigmoidf_fast(float x) {
  return 1.f / (1.f + __expf(-x));
}
__device__ __forceinline__ float tanhf_fast(float x) {
  float e = __expf(2.f * x);
  return 1.f - 2.f / (e + 1.f);
}
__device__ __forceinline__ unsigned pack2(float a, float b) {
  unsigned short ua = __builtin_bit_cast(unsigned short, (__bf16)a);
  unsigned short ub = __builtin_bit_cast(unsigned short, (__bf16)b);
  return (unsigned)ua | ((unsigned)ub << 16);
}

// Wt[tap][oc][ci] = (bf16)W[oc][ci][tap], tap = ky*3+kx  (k-contiguous A rows)
__global__ void transpose_w_kernel(const float* __restrict__ Wsrc,
                                   __bf16* __restrict__ Wt, int C4, int C2) {
  int idx = blockIdx.x * 256 + threadIdx.x;
  int total = C4 * C2 * 9;
  if (idx >= total) return;
  int tap = idx / (C4 * C2);
  int rem = idx - tap * (C4 * C2);
  int oc = rem / C2;
  int ci = rem - oc * C2;
  Wt[idx] = (__bf16)Wsrc[(oc * C2 + ci) * 9 + tap];
}

__global__ void combine_kernel(const float* __restrict__ hf,
                               const float* __restrict__ hb,
                               float* __restrict__ out, int n) {
  int idx = blockIdx.x * 256 + threadIdx.x;
  if (idx >= n) return;
  out[idx] = (hf[idx] + hb[idx]) * 0.5f;
}

// level-1: image 6*34*264*2 = 107712 + A dbuf 2*256*40*2 = 40960  -> 148672
// level-0: image 4*66*136*2 =  71808 + A dbuf 2*256*72*2 = 73728  -> 145536
constexpr int SMEM_BYTES = 148672;

// Block = (dir d, c-slice cs of 64 channels, batch b, OROWS rows) -> N=128 px,
// M=256 oc (64 ch x 4 gates). 8 waves = 2 N-groups (rg) x 4 c-waves (wvr).
// K-loop: one barrier per chunk; next chunk's A prefetched into VGPRs during
// MFMAs, ds_written to the other LDS buffer just before the barrier.
template <int C, int H, int W, int OROWS, int KC, int CS>
__device__ __forceinline__ void convlstm_block(
    char* smem, const float* __restrict__ x_t, int maskv,
    const __bf16* __restrict__ Wt, const float* __restrict__ bias,
    const float* __restrict__ h_in, float* __restrict__ h_out,
    float* __restrict__ c_st, int d, int b, int y0, int cs)
{
  constexpr int Bz = 8, C2 = 2 * C, C4 = 4 * C;
  constexpr int COLS = W + 2, C2p = C2 + 8, IMR = OROWS + 2;
  constexpr int PLANE = H * W, CHW = C * PLANE;
  constexpr int AP = KC + 8;          // A-slab k-stride (pad -> 2-way-free reads)
  constexpr int ABUF = 256 * AP;      // elements per A buffer (OCB = 256 rows)
  constexpr int CPK = C2 / KC;        // chunks per tap
  constexpr int NCH = 9 * CPK;
  constexpr int ITERS = KC / 16;      // A-stage: 16B per thread per iter
  constexpr int PPI = KC / 8;         // 16B parts per A row
  constexpr int CTPR = (W / 16) < 4 ? (W / 16) : 4;
  constexpr int RPG = OROWS / 2;
  constexpr int W4 = W / 4;
  constexpr int IMG_ITERS = (C2 / 4) * IMR * W / 512;

  __bf16* sT = (__bf16*)smem;
  __bf16* sA = (__bf16*)(smem + (size_t)IMR * COLS * C2p * 2);

  const int tid = threadIdx.x;
  const float* hin_b = h_in + (size_t)(d * Bz + b) * CHW;
  float* hout_b = h_out + (size_t)(d * Bz + b) * CHW;

  if (maskv <= 0) {
    // carry this block's 64 channels x OROWS rows (c in-place, untouched)
    for (int u = tid; u < 64 * OROWS * W4; u += 512) {
      int c = cs * 64 + u / (OROWS * W4);
      int rem = u % (OROWS * W4);
      int r = rem / W4, xu = rem % W4;
      size_t off = (size_t)c * PLANE + (size_t)(y0 + r) * W + xu * 4;
      *reinterpret_cast<float4*>(hout_b + off) =
          *reinterpret_cast<const float4*>(hin_b + off);
    }
    return;
  }

  const __bf16* Wtd = Wt + (size_t)d * (9 * C4 * C2);

  // per-thread A-staging constants (slab row aoc = g*64 + c_local)
  int src_off[ITERS], dst_off[ITERS];
#pragma unroll
  for (int it = 0; it < ITERS; ++it) {
    int u = it * 512 + tid;
    int aoc = u / PPI, part = u % PPI;
    int gg = aoc >> 6, cl = aoc & 63;
    src_off[it] = (gg * C + cs * 64 + cl) * C2 + part * 8;
    dst_off[it] = aoc * AP + part * 8;
  }

  // issue A chunk-0 loads early
  uint4 aReg[ITERS];
#pragma unroll
  for (int it = 0; it < ITERS; ++it)
    aReg[it] = *reinterpret_cast<const uint4*>(Wtd + src_off[it]);

  // ---- stage bf16([x | h]) window, transposed [row][slot][ci] ----
  // thread handles 4 consecutive ci at one pixel -> one ds_write_b64
  // (lane stride C2p elem = 132 dw == 4 mod 32: ~8-way, vs 32-way before)
  const float* x_b = x_t + (size_t)b * CHW;
#pragma unroll
  for (int it = 0; it < IMG_ITERS; ++it) {
    int u = it * 512 + tid;
    int x = u % W;
    int t2 = u / W;
    int rr = t2 % IMR, ci4 = t2 / IMR;
    int yy = y0 + rr - 1;
    uint2 pv; pv.x = 0u; pv.y = 0u;
    if (yy >= 0 && yy < H) {
      int ci = ci4 * 4;
      const float* s0 = ((ci < C) ? (x_b + (size_t)ci * PLANE)
                                  : (hin_b + (size_t)(ci - C) * PLANE)) +
                        (size_t)yy * W + x;
      float f0 = s0[0];
      float f1 = s0[PLANE];
      float f2 = s0[2 * PLANE];
      float f3 = s0[3 * PLANE];
      pv.x = pack2(f0, f1);
      pv.y = pack2(f2, f3);
    }
    *reinterpret_cast<uint2*>(&sT[(rr * COLS + x + 1) * C2p + ci4 * 4]) = pv;
  }
  // x halo: slots 0 and W+1 zero
  for (int u = tid; u < (C2 / 4) * IMR * 2; u += 512) {
    int ci4 = u / (IMR * 2);
    int rem = u % (IMR * 2);
    int rr = rem >> 1;
    int slot = (rem & 1) ? (W + 1) : 0;
    uint2 z; z.x = 0u; z.y = 0u;
    *reinterpret_cast<uint2*>(&sT[(rr * COLS + slot) * C2p + ci4 * 4]) = z;
  }
  // commit A chunk 0
#pragma unroll
  for (int it = 0; it < ITERS; ++it)
    *reinterpret_cast<uint4*>(sA + dst_off[it]) = aReg[it];
  __syncthreads();

  const int lane = tid & 63, wv = tid >> 6;
  const int rg = wv >> 2, wvr = wv & 3;
  const int n = lane & 15, q = lane >> 4;

  f32x4 acc[4][4];
  f32x4 zero = {0.f, 0.f, 0.f, 0.f};
#pragma unroll
  for (int g = 0; g < 4; ++g)
#pragma unroll
    for (int nt = 0; nt < 4; ++nt) acc[g][nt] = zero;

  for (int kc = 0; kc < NCH; ++kc) {
    const int tap = kc / CPK, ci0 = (kc % CPK) * KC;
    const int ky = tap / 3, kx = tap - 3 * ky;

    // prefetch next chunk's A into VGPRs (lands during MFMAs below)
    if (kc + 1 < NCH) {
      int ntap = (kc + 1) / CPK, nci0 = ((kc + 1) % CPK) * KC;
      size_t choff = (size_t)ntap * C4 * C2 + nci0;
#pragma unroll
      for (int it = 0; it < ITERS; ++it)
        aReg[it] = *reinterpret_cast<const uint4*>(Wtd + choff + src_off[it]);
    }

    const __bf16* sAb = sA + (kc & 1) * ABUF;
#pragma unroll
    for (int kk = 0; kk < KC / 32; ++kk) {
      bf16x8 bfr[4];
#pragma unroll
      for (int nt = 0; nt < 4; ++nt) {
        int row = rg * RPG + nt / CTPR + ky;
        int slot = (nt % CTPR) * 16 + n + kx;
        bfr[nt] = *reinterpret_cast<const bf16x8*>(
            &sT[(row * COLS + slot) * C2p + ci0 + kk * 32 + q * 8]);
      }
      bf16x8 afr[4];
#pragma unroll
      for (int g = 0; g < 4; ++g)
        afr[g] = *reinterpret_cast<const bf16x8*>(
            &sAb[(g * 64 + wvr * 16 + n) * AP + kk * 32 + q * 8]);
#pragma unroll
      for (int g = 0; g < 4; ++g)
#pragma unroll
        for (int nt = 0; nt < 4; ++nt)
          acc[g][nt] = __builtin_amdgcn_mfma_f32_16x16x32_bf16(
              afr[g], bfr[nt], acc[g][nt], 0, 0, 0);
    }

    // commit prefetched A to the other buffer (vmcnt wait lands here, late)
    if (kc + 1 < NCH) {
      __bf16* sAn = sA + ((kc + 1) & 1) * ABUF;
#pragma unroll
      for (int it = 0; it < ITERS; ++it)
        *reinterpret_cast<uint4*>(sAn + dst_off[it]) = aReg[it];
    }
    __syncthreads();
  }

  // ---- fused LSTM gate epilogue (D: col = n = px, row = q*4+r = channel) ----
  float* c_b = c_st + (size_t)(d * Bz + b) * CHW;
#pragma unroll
  for (int r = 0; r < 4; ++r) {
    const int cg = cs * 64 + wvr * 16 + q * 4 + r;
    const float bi = bias[0 * C + cg];
    const float bff = bias[1 * C + cg];
    const float bo = bias[2 * C + cg];
    const float bg = bias[3 * C + cg];
#pragma unroll
    for (int nt = 0; nt < 4; ++nt) {
      const int y = y0 + rg * RPG + nt / CTPR;
      const int x = (nt % CTPR) * 16 + n;
      const size_t off = (size_t)cg * PLANE + (size_t)y * W + x;
      const float vi = acc[0][nt][r] + bi;
      const float vf = acc[1][nt][r] + bff;
      const float vo = acc[2][nt][r] + bo;
      const float vg = acc[3][nt][r] + bg;
      const float cn = sigmoidf_fast(vf) * c_b[off] + sigmoidf_fast(vi) * tanhf_fast(vg);
      c_b[off] = cn;
      hout_b[off] = sigmoidf_fast(vo) * tanhf_fast(cn);
    }
  }
}

// blocks [0,256) = level-1 (2 dir x 2 cs x 8 b x 8 yb), [256,768) = level-0
// (2 dir x 8 b x 32 yb). dir in the lowest bit -> XCD round-robin per dir.
__global__ __launch_bounds__(512, 2)
void step_kernel(const float* __restrict__ x0, const float* __restrict__ x1,
                 const int* __restrict__ mask_t,
                 const __bf16* __restrict__ Wt0, const __bf16* __restrict__ Wt1,
                 const float* __restrict__ bf0, const float* __restrict__ bb0,
                 const float* __restrict__ bf1, const float* __restrict__ bb1,
                 const float* __restrict__ hin0, float* __restrict__ hout0,
                 float* __restrict__ c0,
                 const float* __restrict__ hin1, float* __restrict__ hout1,
                 float* __restrict__ c1)
{
  __shared__ __align__(16) char smem[SMEM_BYTES];
  const int idx = blockIdx.x;
  if (idx < 256) {
    int d = idx & 1, r = idx >> 1;
    int cs = r & 1; r >>= 1;
    int b = r & 7, yb = r >> 3;       // yb in [0,8): 4 rows each
    convlstm_block<128, 32, 32, 4, 32, 2>(smem, x1, mask_t[b], Wt1,
        d == 0 ? bf1 : bb1, hin1, hout1, c1, d, b, yb * 4, cs);
  } else {
    int j = idx - 256;
    int d = j & 1, r = j >> 1;
    int b = r & 7, yb = r >> 3;       // yb in [0,32): 2 rows each
    convlstm_block<64, 64, 64, 2, 64, 1>(smem, x0, mask_t[b], Wt0,
        d == 0 ? bf0 : bb0, hin0, hout0, c0, d, b, yb * 2, 0);
  }
}

extern "C" void kernel_launch(void* const* d_in, const int* in_sizes, int n_in,
                              void* d_out, int out_size, void* d_ws, size_t ws_size,
                              hipStream_t stream) {
  const float* feat0 = (const float*)d_in[0];
  const float* feat1 = (const float*)d_in[1];
  const int* mask = (const int*)d_in[2];
  const float* Wf0 = (const float*)d_in[3];
  const float* bf0 = (const float*)d_in[4];
  const float* Wb0 = (const float*)d_in[5];
  const float* bb0 = (const float*)d_in[6];
  const float* Wf1 = (const float*)d_in[7];
  const float* bf1 = (const float*)d_in[8];
  const float* Wb1 = (const float*)d_in[9];
  const float* bb1 = (const float*)d_in[10];

  const int T = 16;
  const size_t SZ0 = (size_t)8 * 64 * 64 * 64;   // per-(dir,buf) h elems, level 0
  const size_t SZ1 = (size_t)8 * 128 * 32 * 32;  // level 1
  const size_t WT0 = (size_t)9 * 256 * 128;      // per-dir transposed weights
  const size_t WT1 = (size_t)9 * 512 * 256;

  char* p = (char*)d_ws;
  __bf16* Wt0 = (__bf16*)p; p += 2 * WT0 * sizeof(__bf16);
  __bf16* Wt1 = (__bf16*)p; p += 2 * WT1 * sizeof(__bf16);
  float* h0 = (float*)p;    p += 4 * SZ0 * sizeof(float);   // [buf][dir][B][C][H][W]
  float* h1 = (float*)p;    p += 4 * SZ1 * sizeof(float);
  float* c0 = (float*)p;    p += 2 * SZ0 * sizeof(float);   // [dir][B][C][H][W]
  float* c1 = (float*)p;    p += 2 * SZ1 * sizeof(float);

  hipMemsetAsync(h0, 0, 2 * SZ0 * sizeof(float), stream);
  hipMemsetAsync(h1, 0, 2 * SZ1 * sizeof(float), stream);
  hipMemsetAsync(c0, 0, 2 * SZ0 * sizeof(float), stream);
  hipMemsetAsync(c1, 0, 2 * SZ1 * sizeof(float), stream);

  transpose_w_kernel<<<((int)WT0 + 255) / 256, 256, 0, stream>>>(Wf0, Wt0, 256, 128);
  transpose_w_kernel<<<((int)WT0 + 255) / 256, 256, 0, stream>>>(Wb0, Wt0 + WT0, 256, 128);
  transpose_w_kernel<<<((int)WT1 + 255) / 256, 256, 0, stream>>>(Wf1, Wt1, 512, 256);
  transpose_w_kernel<<<((int)WT1 + 255) / 256, 256, 0, stream>>>(Wb1, Wt1 + WT1, 512, 256);

  for (int t = 0; t < T; ++t) {
    const int pi = t & 1, po = 1 - pi;
    step_kernel<<<768, 512, 0, stream>>>(
        feat0 + (size_t)t * SZ0, feat1 + (size_t)t * SZ1, mask + t * 8,
        Wt0, Wt1, bf0, bb0, bf1, bb1,
        h0 + (size_t)pi * 2 * SZ0, h0 + (size_t)po * 2 * SZ0, c0,
        h1 + (size_t)pi * 2 * SZ1, h1 + (size_t)po * 2 * SZ1, c1);
  }

  // T=16 is even -> final states live in buf 0
  float* out = (float*)d_out;
  combine_kernel<<<((int)SZ0 + 255) / 256, 256, 0, stream>>>(h0, h0 + SZ0, out, (int)SZ0);
  combine_kernel<<<((int)SZ1 + 255) / 256, 256, 0, stream>>>(h1, h1 + SZ1, out + SZ0, (int)SZ1);
}